// Round 2
// baseline (2224.499 us; speedup 1.0000x reference)
//
#include <hip/hip_runtime.h>
#include <math.h>

#define NN 27
#define HID 128
#define HS 132           // padded row stride (floats) for h1/H: 4-row groups land 16 banks apart -> free 2-way
#define SITERS 20

typedef float v4 __attribute__((ext_vector_type(4)));

// ---------------- Kernel 1: features + MLP + scores -> exp(log_alpha) into d_out ----------------
// block = 128 threads, one batch element per block. One LDS buffer, sequential lifetimes:
//   [P0] A staging (729 f) -> [P2] h1 (28 x HS) -> [P5a] normalized H (27 x HS)
__global__ __launch_bounds__(128, 3) void k1_mlp(
    const float* __restrict__ A, const float* __restrict__ m,
    const float* __restrict__ tau_r,
    const float* __restrict__ ln1g, const float* __restrict__ ln1b,
    const float* __restrict__ W1, const float* __restrict__ b1,
    const float* __restrict__ W2, const float* __restrict__ b2,
    const float* __restrict__ ln2g, const float* __restrict__ ln2b,
    const float* __restrict__ protos, float* __restrict__ out)
{
    __shared__ __align__(16) float sBuf[28 * HS];       // 14.8 KB unified buffer
    __shared__ __align__(16) float sFeat[NN * 4 + 4];

    const int b   = blockIdx.x;
    const int tid = threadIdx.x;
    const float* Ab = A + (size_t)b * (NN * NN);

    // ---- P0: stage A (729 floats) ----
    float* sA = sBuf;
    for (int i = tid; i < NN * NN; i += 128) sA[i] = Ab[i];
    __syncthreads();

    // ---- P1: per-row features [log1p(rowsum), top1_offdiag, top2_offdiag, m], then LN1 ----
    if (tid < NN) {
        const int n = tid;
        float sum = 0.f, m1 = -1e30f, m2 = -1e30f;
        #pragma unroll
        for (int j = 0; j < NN; ++j) {
            float a = sA[n * NN + j];
            sum += a;
            float v = (j == n) ? 0.f : a;
            float nm1 = fmaxf(m1, v);
            m2 = fmaxf(m2, fminf(m1, v));
            m1 = nm1;
        }
        float f0 = log1pf(sum), f1 = m1, f2 = m2, f3 = m[(size_t)b * NN + n];
        float mu = 0.25f * (f0 + f1 + f2 + f3);
        float d0 = f0 - mu, d1 = f1 - mu, d2 = f2 - mu, d3 = f3 - mu;
        float var = 0.25f * (d0*d0 + d1*d1 + d2*d2 + d3*d3);
        float rs  = rsqrtf(var + 1e-5f);
        sFeat[n*4 + 0] = d0 * rs * ln1g[0] + ln1b[0];
        sFeat[n*4 + 1] = d1 * rs * ln1g[1] + ln1b[1];
        sFeat[n*4 + 2] = d2 * rs * ln1g[2] + ln1b[2];
        sFeat[n*4 + 3] = d3 * rs * ln1g[3] + ln1b[3];
    }
    __syncthreads();

    // ---- P2: h1 = relu(featLN @ W1 + b1) into sBuf (stride HS); zero pad row 27 ----
    {
        const float w0 = W1[tid], w1 = W1[HID + tid], w2 = W1[2*HID + tid], w3 = W1[3*HID + tid];
        const float bb = b1[tid];
        #pragma unroll 9
        for (int n = 0; n < NN; ++n) {
            v4 f = *(const v4*)&sFeat[n * 4];
            float v = fmaf(f[0], w0, fmaf(f[1], w1, fmaf(f[2], w2, fmaf(f[3], w3, bb))));
            sBuf[n * HS + tid] = fmaxf(v, 0.f);
        }
        sBuf[27 * HS + tid] = 0.f;
    }
    __syncthreads();

    // ---- P3: h2 = h1 @ W2 + b2. Register tile: 4 rows x 8 cols per thread. ----
    const int tcol = tid & 15, g = tid >> 4;
    const int n0 = (g < 7 ? g : 6) * 4;
    const int t0 = tcol * 8;
    v4 acc[4][2];
    {
        v4 ba = *(const v4*)&b2[t0], bb2 = *(const v4*)&b2[t0 + 4];
        #pragma unroll
        for (int nn = 0; nn < 4; ++nn) { acc[nn][0] = ba; acc[nn][1] = bb2; }
        for (int k = 0; k < HID; k += 4) {
            v4 h[4];
            #pragma unroll
            for (int nn = 0; nn < 4; ++nn) h[nn] = *(const v4*)&sBuf[(n0 + nn) * HS + k];
            #pragma unroll
            for (int kk = 0; kk < 4; ++kk) {
                const float* wr = &W2[(k + kk) * HID + t0];
                v4 wa = *(const v4*)wr;
                v4 wb = *(const v4*)(wr + 4);
                #pragma unroll
                for (int nn = 0; nn < 4; ++nn) {
                    float hv = h[nn][kk];
                    acc[nn][0] += hv * wa;
                    acc[nn][1] += hv * wb;
                }
            }
        }
    }
    __syncthreads();   // all h1 reads done; sBuf can be overwritten with H

    // ---- P4: LN2 stats in-register: reduce over the 16 lanes owning each row ----
    // lanes (g%4)*16 .. +15 within a wave hold row group n0; xor masks 1,2,4,8 stay in-group.
    {
        v4 g2a = *(const v4*)&ln2g[t0], g2b = *(const v4*)&ln2g[t0 + 4];
        v4 ba2 = *(const v4*)&ln2b[t0], bb3 = *(const v4*)&ln2b[t0 + 4];
        #pragma unroll
        for (int nn = 0; nn < 4; ++nn) {
            v4 a0 = acc[nn][0], a1 = acc[nn][1];
            float s  = a0[0]+a0[1]+a0[2]+a0[3] + a1[0]+a1[1]+a1[2]+a1[3];
            float ss = a0[0]*a0[0]+a0[1]*a0[1]+a0[2]*a0[2]+a0[3]*a0[3]
                     + a1[0]*a1[0]+a1[1]*a1[1]+a1[2]*a1[2]+a1[3]*a1[3];
            #pragma unroll
            for (int mask = 1; mask <= 8; mask <<= 1) {
                s  += __shfl_xor(s,  mask);
                ss += __shfl_xor(ss, mask);
            }
            float mu  = s * (1.0f / HID);
            float var = ss * (1.0f / HID) - mu * mu;
            float rs  = rsqrtf(var + 1e-5f);
            int n = n0 + nn;
            if (n < NN) {
                *(v4*)&sBuf[n * HS + t0]     = (a0 - mu) * rs * g2a + ba2;
                *(v4*)&sBuf[n * HS + t0 + 4] = (a1 - mu) * rs * g2b + bb3;
            }
        }
    }
    __syncthreads();

    // ---- P5: out[i][j] = exp((H[j] . protos[i]) / tau)  (linear-domain P for Sinkhorn) ----
    const float inv_tau = 1.0f / tau_r[0];
    if (tid < 126) {
        const int ig = tid / 9, jg = tid - ig * 9;
        const int i0 = ig * 2, j0 = jg * 3;
        const int i1 = i0 + 1;
        const int i1c = (i1 < NN) ? i1 : (NN - 1);
        v4 va[2][3];
        #pragma unroll
        for (int ii = 0; ii < 2; ++ii)
            #pragma unroll
            for (int jj = 0; jj < 3; ++jj) va[ii][jj] = (v4)(0.f);
        for (int k = 0; k < HID; k += 4) {
            v4 hq0 = *(const v4*)&sBuf[(j0 + 0) * HS + k];
            v4 hq1 = *(const v4*)&sBuf[(j0 + 1) * HS + k];
            v4 hq2 = *(const v4*)&sBuf[(j0 + 2) * HS + k];
            v4 pa  = *(const v4*)&protos[i0  * HID + k];
            v4 pb  = *(const v4*)&protos[i1c * HID + k];
            va[0][0] += hq0 * pa; va[0][1] += hq1 * pa; va[0][2] += hq2 * pa;
            va[1][0] += hq0 * pb; va[1][1] += hq1 * pb; va[1][2] += hq2 * pb;
        }
        float* ob = out + (size_t)b * (NN * NN);
        #pragma unroll
        for (int ii = 0; ii < 2; ++ii) {
            int i = i0 + ii;
            if (i < NN) {
                #pragma unroll
                for (int jj = 0; jj < 3; ++jj) {
                    v4 t = va[ii][jj];
                    ob[i * NN + (j0 + jj)] = __expf((t[0] + t[1] + t[2] + t[3]) * inv_tau);
                }
            }
        }
    }
}

// ---------------- Kernel 2: LINEAR-domain Sinkhorn (20 iters), in-place on P ----------------
// block = 256 threads = 4 waves; 2 elements per wave (32-lane halves), wave_barrier only.
// Column scale factors c[] are deferred into the next row pass (no column writes).
#define ES 800   // element stride in LDS floats: 27 rows x 28 + c[28] at offset 756
__global__ __launch_bounds__(256) void k2_sinkhorn(float* __restrict__ la, int B)
{
    __shared__ __align__(16) float sLa[8 * ES];

    const int w = threadIdx.x >> 6;
    const int l = threadIdx.x & 63;
    const int half = l >> 5, r = l & 31;
    const int eb = blockIdx.x * 8 + w * 2;
    if (eb >= B) return;
    const int nel = (B - eb >= 2) ? 2 : 1;

    float* sw = sLa + (w * 2) * ES;
    const size_t gbase = (size_t)eb * (NN * NN);

    // load P (stride 27 -> 28), init c = 1 and pad col = 0
    for (int idx = l; idx < nel * NN * NN; idx += 64) {
        int e = (idx >= NN * NN) ? 1 : 0;
        int p = idx - e * (NN * NN);
        int row = p / NN, col = p - row * NN;
        sw[e * ES + row * 28 + col] = la[gbase + idx];
    }
    for (int idx = l; idx < nel * 28; idx += 64) {
        int e = (idx >= 28) ? 1 : 0;
        int j = idx - e * 28;
        sw[e * ES + 756 + j] = 1.f;
        if (j < NN) sw[e * ES + j * 28 + NN] = 0.f;
    }
    __builtin_amdgcn_wave_barrier();

    float* se = sw + half * ES;
    float* ce = se + 756;
    const bool act = (r < NN) && (half < nel);

    for (int it = 0; it < SITERS; ++it) {
        // row pass: apply pending col factors, row-normalize. Lane r owns row r (contiguous).
        if (act) {
            float* rp = se + r * 28;
            v4 x[7], cc[7];
            #pragma unroll
            for (int qi = 0; qi < 7; ++qi) { x[qi] = *(const v4*)&rp[qi * 4]; cc[qi] = *(const v4*)&ce[qi * 4]; }
            #pragma unroll
            for (int qi = 0; qi < 7; ++qi) x[qi] *= cc[qi];
            float s = 0.f;
            #pragma unroll
            for (int qi = 0; qi < 6; ++qi) s += x[qi][0] + x[qi][1] + x[qi][2] + x[qi][3];
            s += x[6][0] + x[6][1] + x[6][2];
            float rho = 1.0f / s;
            #pragma unroll
            for (int qi = 0; qi < 7; ++qi) *(v4*)&rp[qi * 4] = x[qi] * rho;
        }
        __builtin_amdgcn_wave_barrier();
        // col pass: compute new col factors only (no writes to the matrix). Lane r owns col r.
        if (act) {
            const float* cp = se + r;
            float s = 0.f;
            #pragma unroll
            for (int i = 0; i < NN; ++i) s += cp[i * 28];
            ce[r] = 1.0f / s;
        }
        __builtin_amdgcn_wave_barrier();
    }

    // final store: apply pending col factors, coalesced
    for (int idx = l; idx < nel * NN * NN; idx += 64) {
        int e = (idx >= NN * NN) ? 1 : 0;
        int p = idx - e * (NN * NN);
        int row = p / NN, col = p - row * NN;
        la[gbase + idx] = sw[e * ES + row * 28 + col] * sw[e * ES + 756 + col];
    }
}

extern "C" void kernel_launch(void* const* d_in, const int* in_sizes, int n_in,
                              void* d_out, int out_size, void* d_ws, size_t ws_size,
                              hipStream_t stream) {
    const float* A      = (const float*)d_in[0];
    const float* m      = (const float*)d_in[1];
    const float* tau_r  = (const float*)d_in[2];
    const float* ln1g   = (const float*)d_in[3];
    const float* ln1b   = (const float*)d_in[4];
    const float* W1     = (const float*)d_in[5];
    const float* b1     = (const float*)d_in[6];
    const float* W2     = (const float*)d_in[7];
    const float* b2     = (const float*)d_in[8];
    const float* ln2g   = (const float*)d_in[9];
    const float* ln2b   = (const float*)d_in[10];
    const float* protos = (const float*)d_in[11];
    float* out = (float*)d_out;

    const int B = in_sizes[0] / (NN * NN);

    k1_mlp<<<B, 128, 0, stream>>>(A, m, tau_r, ln1g, ln1b, W1, b1, W2, b2,
                                  ln2g, ln2b, protos, out);
    const int blocks2 = (B + 7) / 8;
    k2_sinkhorn<<<blocks2, 256, 0, stream>>>(out, B);
}

// Round 3
// 1988.191 us; speedup vs baseline: 1.1189x; 1.1189x over previous
//
#include <hip/hip_runtime.h>
#include <math.h>

#define NN 27
#define HID 128
#define HS 132           // padded row stride (floats) for h1/H: 4-row groups land 16 banks apart -> free 2-way
#define SITERS 20

typedef float v4 __attribute__((ext_vector_type(4)));

// ---------------- Kernel 1: features + MLP + scores -> exp(log_alpha) into d_out ----------------
// block = 128 threads, one batch element per block. One LDS buffer, sequential lifetimes:
//   [P0] A staging (729 f) -> [P2] h1 (28 x HS) -> [P5a] normalized H (27 x HS)
// __launch_bounds__(128, 2): empirically arg=3 -> 84-VGPR cap (spill disaster, R2);
// arg=2 -> ~128 cap = 4 waves/EU, enough for the ~100-reg working set.
__global__ __launch_bounds__(128, 2) void k1_mlp(
    const float* __restrict__ A, const float* __restrict__ m,
    const float* __restrict__ tau_r,
    const float* __restrict__ ln1g, const float* __restrict__ ln1b,
    const float* __restrict__ W1, const float* __restrict__ b1,
    const float* __restrict__ W2, const float* __restrict__ b2,
    const float* __restrict__ ln2g, const float* __restrict__ ln2b,
    const float* __restrict__ protos, float* __restrict__ out)
{
    __shared__ __align__(16) float sBuf[28 * HS];       // 14.8 KB unified buffer
    __shared__ __align__(16) float sFeat[NN * 4 + 4];

    const int b   = blockIdx.x;
    const int tid = threadIdx.x;
    const float* Ab = A + (size_t)b * (NN * NN);

    // ---- P0: stage A (729 floats) ----
    float* sA = sBuf;
    for (int i = tid; i < NN * NN; i += 128) sA[i] = Ab[i];
    __syncthreads();

    // ---- P1: per-row features [log1p(rowsum), top1_offdiag, top2_offdiag, m], then LN1 ----
    if (tid < NN) {
        const int n = tid;
        float sum = 0.f, m1 = -1e30f, m2 = -1e30f;
        #pragma unroll
        for (int j = 0; j < NN; ++j) {
            float a = sA[n * NN + j];
            sum += a;
            float v = (j == n) ? 0.f : a;
            float nm1 = fmaxf(m1, v);
            m2 = fmaxf(m2, fminf(m1, v));
            m1 = nm1;
        }
        float f0 = log1pf(sum), f1 = m1, f2 = m2, f3 = m[(size_t)b * NN + n];
        float mu = 0.25f * (f0 + f1 + f2 + f3);
        float d0 = f0 - mu, d1 = f1 - mu, d2 = f2 - mu, d3 = f3 - mu;
        float var = 0.25f * (d0*d0 + d1*d1 + d2*d2 + d3*d3);
        float rs  = rsqrtf(var + 1e-5f);
        sFeat[n*4 + 0] = d0 * rs * ln1g[0] + ln1b[0];
        sFeat[n*4 + 1] = d1 * rs * ln1g[1] + ln1b[1];
        sFeat[n*4 + 2] = d2 * rs * ln1g[2] + ln1b[2];
        sFeat[n*4 + 3] = d3 * rs * ln1g[3] + ln1b[3];
    }
    __syncthreads();

    // ---- P2: h1 = relu(featLN @ W1 + b1) into sBuf (stride HS); zero pad row 27 ----
    {
        const float w0 = W1[tid], w1 = W1[HID + tid], w2 = W1[2*HID + tid], w3 = W1[3*HID + tid];
        const float bb = b1[tid];
        #pragma unroll 9
        for (int n = 0; n < NN; ++n) {
            v4 f = *(const v4*)&sFeat[n * 4];
            float v = fmaf(f[0], w0, fmaf(f[1], w1, fmaf(f[2], w2, fmaf(f[3], w3, bb))));
            sBuf[n * HS + tid] = fmaxf(v, 0.f);
        }
        sBuf[27 * HS + tid] = 0.f;
    }
    __syncthreads();

    // ---- P3: h2 = h1 @ W2 + b2. Register tile: 4 rows x 8 cols per thread. ----
    const int tcol = tid & 15, g = tid >> 4;
    const int n0 = (g < 7 ? g : 6) * 4;
    const int t0 = tcol * 8;
    v4 acc[4][2];
    {
        v4 ba = *(const v4*)&b2[t0], bb2 = *(const v4*)&b2[t0 + 4];
        #pragma unroll
        for (int nn = 0; nn < 4; ++nn) { acc[nn][0] = ba; acc[nn][1] = bb2; }
        for (int k = 0; k < HID; k += 4) {
            v4 h[4];
            #pragma unroll
            for (int nn = 0; nn < 4; ++nn) h[nn] = *(const v4*)&sBuf[(n0 + nn) * HS + k];
            #pragma unroll
            for (int kk = 0; kk < 4; ++kk) {
                const float* wr = &W2[(k + kk) * HID + t0];
                v4 wa = *(const v4*)wr;
                v4 wb = *(const v4*)(wr + 4);
                #pragma unroll
                for (int nn = 0; nn < 4; ++nn) {
                    float hv = h[nn][kk];
                    acc[nn][0] += hv * wa;
                    acc[nn][1] += hv * wb;
                }
            }
        }
    }
    __syncthreads();   // all h1 reads done; sBuf can be overwritten with H

    // ---- P4: LN2 stats in-register: reduce over the 16 lanes owning each row ----
    {
        v4 g2a = *(const v4*)&ln2g[t0], g2b = *(const v4*)&ln2g[t0 + 4];
        v4 ba2 = *(const v4*)&ln2b[t0], bb3 = *(const v4*)&ln2b[t0 + 4];
        #pragma unroll
        for (int nn = 0; nn < 4; ++nn) {
            v4 a0 = acc[nn][0], a1 = acc[nn][1];
            float s  = a0[0]+a0[1]+a0[2]+a0[3] + a1[0]+a1[1]+a1[2]+a1[3];
            float ss = a0[0]*a0[0]+a0[1]*a0[1]+a0[2]*a0[2]+a0[3]*a0[3]
                     + a1[0]*a1[0]+a1[1]*a1[1]+a1[2]*a1[2]+a1[3]*a1[3];
            #pragma unroll
            for (int mask = 1; mask <= 8; mask <<= 1) {
                s  += __shfl_xor(s,  mask);
                ss += __shfl_xor(ss, mask);
            }
            float mu  = s * (1.0f / HID);
            float var = ss * (1.0f / HID) - mu * mu;
            float rs  = rsqrtf(var + 1e-5f);
            int n = n0 + nn;
            if (n < NN) {
                *(v4*)&sBuf[n * HS + t0]     = (a0 - mu) * rs * g2a + ba2;
                *(v4*)&sBuf[n * HS + t0 + 4] = (a1 - mu) * rs * g2b + bb3;
            }
        }
    }
    __syncthreads();

    // ---- P5: out[i][j] = exp((H[j] . protos[i]) / tau)  (linear-domain P for Sinkhorn) ----
    const float inv_tau = 1.0f / tau_r[0];
    if (tid < 126) {
        const int ig = tid / 9, jg = tid - ig * 9;
        const int i0 = ig * 2, j0 = jg * 3;
        const int i1 = i0 + 1;
        const int i1c = (i1 < NN) ? i1 : (NN - 1);
        v4 va[2][3];
        #pragma unroll
        for (int ii = 0; ii < 2; ++ii)
            #pragma unroll
            for (int jj = 0; jj < 3; ++jj) va[ii][jj] = (v4)(0.f);
        for (int k = 0; k < HID; k += 4) {
            v4 hq0 = *(const v4*)&sBuf[(j0 + 0) * HS + k];
            v4 hq1 = *(const v4*)&sBuf[(j0 + 1) * HS + k];
            v4 hq2 = *(const v4*)&sBuf[(j0 + 2) * HS + k];
            v4 pa  = *(const v4*)&protos[i0  * HID + k];
            v4 pb  = *(const v4*)&protos[i1c * HID + k];
            va[0][0] += hq0 * pa; va[0][1] += hq1 * pa; va[0][2] += hq2 * pa;
            va[1][0] += hq0 * pb; va[1][1] += hq1 * pb; va[1][2] += hq2 * pb;
        }
        float* ob = out + (size_t)b * (NN * NN);
        #pragma unroll
        for (int ii = 0; ii < 2; ++ii) {
            int i = i0 + ii;
            if (i < NN) {
                #pragma unroll
                for (int jj = 0; jj < 3; ++jj) {
                    v4 t = va[ii][jj];
                    ob[i * NN + (j0 + jj)] = __expf((t[0] + t[1] + t[2] + t[3]) * inv_tau);
                }
            }
        }
    }
}

// ---------------- Kernel 2: LINEAR-domain Sinkhorn (20 iters), in-place on P ----------------
// block = 256 threads = 4 waves; 2 elements per wave (32-lane halves), wave_barrier only.
// Column scale factors c[] are deferred into the next row pass (no column writes).
#define ES 800   // element stride in LDS floats: 27 rows x 28 + c[28] at offset 756
__global__ __launch_bounds__(256) void k2_sinkhorn(float* __restrict__ la, int B)
{
    __shared__ __align__(16) float sLa[8 * ES];

    const int w = threadIdx.x >> 6;
    const int l = threadIdx.x & 63;
    const int half = l >> 5, r = l & 31;
    const int eb = blockIdx.x * 8 + w * 2;
    if (eb >= B) return;
    const int nel = (B - eb >= 2) ? 2 : 1;

    float* sw = sLa + (w * 2) * ES;
    const size_t gbase = (size_t)eb * (NN * NN);

    // load P (stride 27 -> 28), init c = 1 and pad col = 0
    for (int idx = l; idx < nel * NN * NN; idx += 64) {
        int e = (idx >= NN * NN) ? 1 : 0;
        int p = idx - e * (NN * NN);
        int row = p / NN, col = p - row * NN;
        sw[e * ES + row * 28 + col] = la[gbase + idx];
    }
    for (int idx = l; idx < nel * 28; idx += 64) {
        int e = (idx >= 28) ? 1 : 0;
        int j = idx - e * 28;
        sw[e * ES + 756 + j] = 1.f;
        if (j < NN) sw[e * ES + j * 28 + NN] = 0.f;
    }
    __builtin_amdgcn_wave_barrier();

    float* se = sw + half * ES;
    float* ce = se + 756;
    const bool act = (r < NN) && (half < nel);

    for (int it = 0; it < SITERS; ++it) {
        // row pass: apply pending col factors, row-normalize. Lane r owns row r (contiguous).
        if (act) {
            float* rp = se + r * 28;
            v4 x[7], cc[7];
            #pragma unroll
            for (int qi = 0; qi < 7; ++qi) { x[qi] = *(const v4*)&rp[qi * 4]; cc[qi] = *(const v4*)&ce[qi * 4]; }
            #pragma unroll
            for (int qi = 0; qi < 7; ++qi) x[qi] *= cc[qi];
            float s = 0.f;
            #pragma unroll
            for (int qi = 0; qi < 6; ++qi) s += x[qi][0] + x[qi][1] + x[qi][2] + x[qi][3];
            s += x[6][0] + x[6][1] + x[6][2];
            float rho = 1.0f / s;
            #pragma unroll
            for (int qi = 0; qi < 7; ++qi) *(v4*)&rp[qi * 4] = x[qi] * rho;
        }
        __builtin_amdgcn_wave_barrier();
        // col pass: compute new col factors only (no writes to the matrix). Lane r owns col r.
        if (act) {
            const float* cp = se + r;
            float s = 0.f;
            #pragma unroll
            for (int i = 0; i < NN; ++i) s += cp[i * 28];
            ce[r] = 1.0f / s;
        }
        __builtin_amdgcn_wave_barrier();
    }

    // final store: apply pending col factors, coalesced
    for (int idx = l; idx < nel * NN * NN; idx += 64) {
        int e = (idx >= NN * NN) ? 1 : 0;
        int p = idx - e * (NN * NN);
        int row = p / NN, col = p - row * NN;
        la[gbase + idx] = sw[e * ES + row * 28 + col] * sw[e * ES + 756 + col];
    }
}

extern "C" void kernel_launch(void* const* d_in, const int* in_sizes, int n_in,
                              void* d_out, int out_size, void* d_ws, size_t ws_size,
                              hipStream_t stream) {
    const float* A      = (const float*)d_in[0];
    const float* m      = (const float*)d_in[1];
    const float* tau_r  = (const float*)d_in[2];
    const float* ln1g   = (const float*)d_in[3];
    const float* ln1b   = (const float*)d_in[4];
    const float* W1     = (const float*)d_in[5];
    const float* b1     = (const float*)d_in[6];
    const float* W2     = (const float*)d_in[7];
    const float* b2     = (const float*)d_in[8];
    const float* ln2g   = (const float*)d_in[9];
    const float* ln2b   = (const float*)d_in[10];
    const float* protos = (const float*)d_in[11];
    float* out = (float*)d_out;

    const int B = in_sizes[0] / (NN * NN);

    k1_mlp<<<B, 128, 0, stream>>>(A, m, tau_r, ln1g, ln1b, W1, b1, W2, b2,
                                  ln2g, ln2b, protos, out);
    const int blocks2 = (B + 7) / 8;
    k2_sinkhorn<<<blocks2, 256, 0, stream>>>(out, B);
}

// Round 4
// 932.242 us; speedup vs baseline: 2.3862x; 2.1327x over previous
//
#include <hip/hip_runtime.h>
#include <math.h>

#define NN 27
#define HID 128
#define HS 132           // padded row stride (floats) for h1/H: 4-row groups land 16 banks apart -> free 2-way
#define SITERS 20

typedef float v4 __attribute__((ext_vector_type(4)));

// ---------------- Kernel 1: features + MLP + scores -> exp(log_alpha) into d_out ----------------
// block = 128 threads, one batch element per block. One LDS buffer, sequential lifetimes:
//   [P0] A staging (729 f) -> [P2] h1 (28 x HS) -> [P5a] normalized H (27 x HS)
// __launch_bounds__(128,2) -> 128-VGPR cap (R2: arg=3 gave 84+spill disaster; R3: cap=128 but
// full unroll of P3 k-loop kept ~200 regs of W2 loads live -> still spilled 4 GB).
// Fix: #pragma unroll 1 on the k-loop caps the live-load window at one iteration (~110 regs).
__global__ __launch_bounds__(128, 2) void k1_mlp(
    const float* __restrict__ A, const float* __restrict__ m,
    const float* __restrict__ tau_r,
    const float* __restrict__ ln1g, const float* __restrict__ ln1b,
    const float* __restrict__ W1, const float* __restrict__ b1,
    const float* __restrict__ W2, const float* __restrict__ b2,
    const float* __restrict__ ln2g, const float* __restrict__ ln2b,
    const float* __restrict__ protos, float* __restrict__ out)
{
    __shared__ __align__(16) float sBuf[28 * HS];       // 14.8 KB unified buffer
    __shared__ __align__(16) float sFeat[NN * 4 + 4];

    const int b   = blockIdx.x;
    const int tid = threadIdx.x;
    const float* Ab = A + (size_t)b * (NN * NN);

    // ---- P0: stage A (729 floats) ----
    float* sA = sBuf;
    for (int i = tid; i < NN * NN; i += 128) sA[i] = Ab[i];
    __syncthreads();

    // ---- P1: per-row features [log1p(rowsum), top1_offdiag, top2_offdiag, m], then LN1 ----
    if (tid < NN) {
        const int n = tid;
        float sum = 0.f, m1 = -1e30f, m2 = -1e30f;
        #pragma unroll
        for (int j = 0; j < NN; ++j) {
            float a = sA[n * NN + j];
            sum += a;
            float v = (j == n) ? 0.f : a;
            float nm1 = fmaxf(m1, v);
            m2 = fmaxf(m2, fminf(m1, v));
            m1 = nm1;
        }
        float f0 = log1pf(sum), f1 = m1, f2 = m2, f3 = m[(size_t)b * NN + n];
        float mu = 0.25f * (f0 + f1 + f2 + f3);
        float d0 = f0 - mu, d1 = f1 - mu, d2 = f2 - mu, d3 = f3 - mu;
        float var = 0.25f * (d0*d0 + d1*d1 + d2*d2 + d3*d3);
        float rs  = rsqrtf(var + 1e-5f);
        sFeat[n*4 + 0] = d0 * rs * ln1g[0] + ln1b[0];
        sFeat[n*4 + 1] = d1 * rs * ln1g[1] + ln1b[1];
        sFeat[n*4 + 2] = d2 * rs * ln1g[2] + ln1b[2];
        sFeat[n*4 + 3] = d3 * rs * ln1g[3] + ln1b[3];
    }
    __syncthreads();

    // ---- P2: h1 = relu(featLN @ W1 + b1) into sBuf (stride HS); zero pad row 27 ----
    {
        const float w0 = W1[tid], w1 = W1[HID + tid], w2 = W1[2*HID + tid], w3 = W1[3*HID + tid];
        const float bb = b1[tid];
        #pragma unroll 9
        for (int n = 0; n < NN; ++n) {
            v4 f = *(const v4*)&sFeat[n * 4];
            float v = fmaf(f[0], w0, fmaf(f[1], w1, fmaf(f[2], w2, fmaf(f[3], w3, bb))));
            sBuf[n * HS + tid] = fmaxf(v, 0.f);
        }
        sBuf[27 * HS + tid] = 0.f;
    }
    __syncthreads();

    // ---- P3: h2 = h1 @ W2 + b2. Register tile: 4 rows x 8 cols per thread. ----
    const int tcol = tid & 15, g = tid >> 4;
    const int n0 = (g < 7 ? g : 6) * 4;
    const int t0 = tcol * 8;
    v4 acc[4][2];
    {
        v4 ba = *(const v4*)&b2[t0], bb2 = *(const v4*)&b2[t0 + 4];
        #pragma unroll
        for (int nn = 0; nn < 4; ++nn) { acc[nn][0] = ba; acc[nn][1] = bb2; }
        // unroll 1: one iteration's loads in flight (~110 live regs) -> no scratch spill.
        #pragma unroll 1
        for (int k = 0; k < HID; k += 4) {
            v4 h[4];
            #pragma unroll
            for (int nn = 0; nn < 4; ++nn) h[nn] = *(const v4*)&sBuf[(n0 + nn) * HS + k];
            #pragma unroll
            for (int kk = 0; kk < 4; ++kk) {
                const float* wr = &W2[(k + kk) * HID + t0];
                v4 wa = *(const v4*)wr;
                v4 wb = *(const v4*)(wr + 4);
                #pragma unroll
                for (int nn = 0; nn < 4; ++nn) {
                    float hv = h[nn][kk];
                    acc[nn][0] += hv * wa;
                    acc[nn][1] += hv * wb;
                }
            }
        }
    }
    __syncthreads();   // all h1 reads done; sBuf can be overwritten with H

    // ---- P4: LN2 stats in-register: reduce over the 16 lanes owning each row ----
    {
        v4 g2a = *(const v4*)&ln2g[t0], g2b = *(const v4*)&ln2g[t0 + 4];
        v4 ba2 = *(const v4*)&ln2b[t0], bb3 = *(const v4*)&ln2b[t0 + 4];
        #pragma unroll
        for (int nn = 0; nn < 4; ++nn) {
            v4 a0 = acc[nn][0], a1 = acc[nn][1];
            float s  = a0[0]+a0[1]+a0[2]+a0[3] + a1[0]+a1[1]+a1[2]+a1[3];
            float ss = a0[0]*a0[0]+a0[1]*a0[1]+a0[2]*a0[2]+a0[3]*a0[3]
                     + a1[0]*a1[0]+a1[1]*a1[1]+a1[2]*a1[2]+a1[3]*a1[3];
            #pragma unroll
            for (int mask = 1; mask <= 8; mask <<= 1) {
                s  += __shfl_xor(s,  mask);
                ss += __shfl_xor(ss, mask);
            }
            float mu  = s * (1.0f / HID);
            float var = ss * (1.0f / HID) - mu * mu;
            float rs  = rsqrtf(var + 1e-5f);
            int n = n0 + nn;
            if (n < NN) {
                *(v4*)&sBuf[n * HS + t0]     = (a0 - mu) * rs * g2a + ba2;
                *(v4*)&sBuf[n * HS + t0 + 4] = (a1 - mu) * rs * g2b + bb3;
            }
        }
    }
    __syncthreads();

    // ---- P5: out[i][j] = exp((H[j] . protos[i]) / tau)  (linear-domain P for Sinkhorn) ----
    const float inv_tau = 1.0f / tau_r[0];
    if (tid < 126) {
        const int ig = tid / 9, jg = tid - ig * 9;
        const int i0 = ig * 2, j0 = jg * 3;
        const int i1 = i0 + 1;
        const int i1c = (i1 < NN) ? i1 : (NN - 1);
        v4 va[2][3];
        #pragma unroll
        for (int ii = 0; ii < 2; ++ii)
            #pragma unroll
            for (int jj = 0; jj < 3; ++jj) va[ii][jj] = (v4)(0.f);
        // live set ~44 regs/iter; unroll 2 keeps it under the cap with some ILP.
        #pragma unroll 2
        for (int k = 0; k < HID; k += 4) {
            v4 hq0 = *(const v4*)&sBuf[(j0 + 0) * HS + k];
            v4 hq1 = *(const v4*)&sBuf[(j0 + 1) * HS + k];
            v4 hq2 = *(const v4*)&sBuf[(j0 + 2) * HS + k];
            v4 pa  = *(const v4*)&protos[i0  * HID + k];
            v4 pb  = *(const v4*)&protos[i1c * HID + k];
            va[0][0] += hq0 * pa; va[0][1] += hq1 * pa; va[0][2] += hq2 * pa;
            va[1][0] += hq0 * pb; va[1][1] += hq1 * pb; va[1][2] += hq2 * pb;
        }
        float* ob = out + (size_t)b * (NN * NN);
        #pragma unroll
        for (int ii = 0; ii < 2; ++ii) {
            int i = i0 + ii;
            if (i < NN) {
                #pragma unroll
                for (int jj = 0; jj < 3; ++jj) {
                    v4 t = va[ii][jj];
                    ob[i * NN + (j0 + jj)] = __expf((t[0] + t[1] + t[2] + t[3]) * inv_tau);
                }
            }
        }
    }
}

// ---------------- Kernel 2: LINEAR-domain Sinkhorn (20 iters), in-place on P ----------------
// block = 256 threads = 4 waves; 2 elements per wave (32-lane halves), wave_barrier only.
// Column scale factors c[] are deferred into the next row pass (no column writes).
#define ES 800   // element stride in LDS floats: 27 rows x 28 + c[28] at offset 756
__global__ __launch_bounds__(256) void k2_sinkhorn(float* __restrict__ la, int B)
{
    __shared__ __align__(16) float sLa[8 * ES];

    const int w = threadIdx.x >> 6;
    const int l = threadIdx.x & 63;
    const int half = l >> 5, r = l & 31;
    const int eb = blockIdx.x * 8 + w * 2;
    if (eb >= B) return;
    const int nel = (B - eb >= 2) ? 2 : 1;

    float* sw = sLa + (w * 2) * ES;
    const size_t gbase = (size_t)eb * (NN * NN);

    // load P (stride 27 -> 28), init c = 1 and pad col = 0
    for (int idx = l; idx < nel * NN * NN; idx += 64) {
        int e = (idx >= NN * NN) ? 1 : 0;
        int p = idx - e * (NN * NN);
        int row = p / NN, col = p - row * NN;
        sw[e * ES + row * 28 + col] = la[gbase + idx];
    }
    for (int idx = l; idx < nel * 28; idx += 64) {
        int e = (idx >= 28) ? 1 : 0;
        int j = idx - e * 28;
        sw[e * ES + 756 + j] = 1.f;
        if (j < NN) sw[e * ES + j * 28 + NN] = 0.f;
    }
    __builtin_amdgcn_wave_barrier();

    float* se = sw + half * ES;
    float* ce = se + 756;
    const bool act = (r < NN) && (half < nel);

    for (int it = 0; it < SITERS; ++it) {
        // row pass: apply pending col factors, row-normalize. Lane r owns row r (contiguous).
        if (act) {
            float* rp = se + r * 28;
            v4 x[7], cc[7];
            #pragma unroll
            for (int qi = 0; qi < 7; ++qi) { x[qi] = *(const v4*)&rp[qi * 4]; cc[qi] = *(const v4*)&ce[qi * 4]; }
            #pragma unroll
            for (int qi = 0; qi < 7; ++qi) x[qi] *= cc[qi];
            float s = 0.f;
            #pragma unroll
            for (int qi = 0; qi < 6; ++qi) s += x[qi][0] + x[qi][1] + x[qi][2] + x[qi][3];
            s += x[6][0] + x[6][1] + x[6][2];
            float rho = 1.0f / s;
            #pragma unroll
            for (int qi = 0; qi < 7; ++qi) *(v4*)&rp[qi * 4] = x[qi] * rho;
        }
        __builtin_amdgcn_wave_barrier();
        // col pass: compute new col factors only (no writes to the matrix). Lane r owns col r.
        if (act) {
            const float* cp = se + r;
            float s = 0.f;
            #pragma unroll
            for (int i = 0; i < NN; ++i) s += cp[i * 28];
            ce[r] = 1.0f / s;
        }
        __builtin_amdgcn_wave_barrier();
    }

    // final store: apply pending col factors, coalesced
    for (int idx = l; idx < nel * NN * NN; idx += 64) {
        int e = (idx >= NN * NN) ? 1 : 0;
        int p = idx - e * (NN * NN);
        int row = p / NN, col = p - row * NN;
        la[gbase + idx] = sw[e * ES + row * 28 + col] * sw[e * ES + 756 + col];
    }
}

extern "C" void kernel_launch(void* const* d_in, const int* in_sizes, int n_in,
                              void* d_out, int out_size, void* d_ws, size_t ws_size,
                              hipStream_t stream) {
    const float* A      = (const float*)d_in[0];
    const float* m      = (const float*)d_in[1];
    const float* tau_r  = (const float*)d_in[2];
    const float* ln1g   = (const float*)d_in[3];
    const float* ln1b   = (const float*)d_in[4];
    const float* W1     = (const float*)d_in[5];
    const float* b1     = (const float*)d_in[6];
    const float* W2     = (const float*)d_in[7];
    const float* b2     = (const float*)d_in[8];
    const float* ln2g   = (const float*)d_in[9];
    const float* ln2b   = (const float*)d_in[10];
    const float* protos = (const float*)d_in[11];
    float* out = (float*)d_out;

    const int B = in_sizes[0] / (NN * NN);

    k1_mlp<<<B, 128, 0, stream>>>(A, m, tau_r, ln1g, ln1b, W1, b1, W2, b2,
                                  ln2g, ln2b, protos, out);
    const int blocks2 = (B + 7) / 8;
    k2_sinkhorn<<<blocks2, 256, 0, stream>>>(out, B);
}